// Round 1
// baseline (247.065 us; speedup 1.0000x reference)
//
#include <hip/hip_runtime.h>

typedef __bf16 bf16x8 __attribute__((ext_vector_type(8)));
typedef float f32x4 __attribute__((ext_vector_type(4)));

#define MFMA16(a, b, c) __builtin_amdgcn_mfma_f32_16x16x32_bf16((a), (b), (c), 0, 0, 0)

#define BN_ROWS 25600   // B*N
#define DH 256
#define INVPI 0.31830988618379067f

__device__ __forceinline__ unsigned short f2bf(float f) {
    unsigned int u = __float_as_uint(f);
    u = u + 0x7FFFu + ((u >> 16) & 1u);   // round-to-nearest-even
    return (unsigned short)(u >> 16);
}

// f(y) = -y + sin^2(y+gamma) = 0.5 - 0.5*cos(2y+2gamma) - y
// v_cos takes revolutions: rev = (y+gamma)/pi ; gp = gamma/pi precomputed
__device__ __forceinline__ float feval(float y, float gp) {
    float u = fmaf(y, INVPI, gp);
    float cc = __builtin_amdgcn_cosf(u);
    return fmaf(-0.5f, cc, 0.5f - y);
}

// ---------------- K0: convert weights to bf16 ----------------
__global__ void k_convert(const float* __restrict__ w2W, const float* __restrict__ w3W,
                          unsigned short* __restrict__ w2bf, unsigned short* __restrict__ w3bbf) {
    int i = blockIdx.x * 256 + threadIdx.x;   // grid covers 262144 + 32768 exactly
    if (i < 262144) {
        w2bf[i] = f2bf(w2W[i]);
    } else {
        int i2 = i - 262144;                  // < 32768
        int j = i2 >> 8, dk = i2 & 255;
        w3bbf[i2] = f2bf(w3W[j * 1280 + 1024 + dk]);  // yt-part of w3 (cols 1024..1279)
    }
}

// ---------------- K1: fused feature + RK4 ODE + pooled interp ----------------
__global__ void __launch_bounds__(256) k_feat_ode(
    const float* __restrict__ x, const float* __restrict__ w1W, const float* __restrict__ w1b,
    const float* __restrict__ wp,
    unsigned short* __restrict__ featbf, unsigned short* __restrict__ ytbf) {

    // pooling coefficients c[g]: softmax(wp) folded through fixed-grid linear interp
    float c[21];
#pragma unroll
    for (int g = 0; g < 21; ++g) c[g] = 0.f;
    {
        float wv[10];
#pragma unroll
        for (int t = 0; t < 10; ++t) wv[t] = wp[t];
        float m = wv[0];
#pragma unroll
        for (int t = 1; t < 10; ++t) m = fmaxf(m, wv[t]);
        float s = 0.f;
#pragma unroll
        for (int t = 0; t < 10; ++t) { wv[t] = __expf(wv[t] - m); s += wv[t]; }
        float inv = 1.f / s;
        const int   idxs[10]  = {0, 2, 4, 6, 8, 11, 13, 15, 17, 19};
        const float fracs[10] = {0.f, 0.22222222f, 0.44444445f, 0.6666667f, 0.8888889f,
                                 0.11111111f, 0.33333334f, 0.5555556f, 0.7777778f, 1.0f};
#pragma unroll
        for (int t = 0; t < 10; ++t) {
            float w = wv[t] * inv;
            c[idxs[t]]     += w * (1.f - fracs[t]);
            c[idxs[t] + 1] += w * fracs[t];
        }
    }

    int tid  = blockIdx.x * 256 + threadIdx.x;    // 1,638,400 threads exactly
    int base = tid * 4;
    int row  = base >> 8;        // 0..25599
    int d0   = base & 255;

    float x0 = x[row * 3 + 0], x1 = x[row * 3 + 1], x2v = x[row * 3 + 2];

    float g_[4], y_[4], a_[4], gp[4];
#pragma unroll
    for (int j = 0; j < 4; ++j) {
        const float* wr = w1W + (d0 + j) * 3;
        float f = fmaf(x0, wr[0], fmaf(x1, wr[1], fmaf(x2v, wr[2], w1b[d0 + j])));
        f = fmaxf(f, 0.f);
        g_[j] = f;
        gp[j] = f * INVPI;
        y_[j] = 0.f;
        a_[j] = 0.f;
    }
    ushort4 fb;
    fb.x = f2bf(g_[0]); fb.y = f2bf(g_[1]); fb.z = f2bf(g_[2]); fb.w = f2bf(g_[3]);
    *reinterpret_cast<ushort4*>(featbf + base) = fb;

#pragma unroll
    for (int st = 0; st < 20; ++st) {
        float cg = c[st + 1];
#pragma unroll
        for (int j = 0; j < 4; ++j) {
            float y  = y_[j];
            float k1 = feval(y, gp[j]);
            float k2 = feval(fmaf(0.05f, k1, y), gp[j]);
            float k3 = feval(fmaf(0.05f, k2, y), gp[j]);
            float k4 = feval(fmaf(0.1f,  k3, y), gp[j]);
            float sm = k1 + k4;
            sm = fmaf(2.f, k2, sm);
            sm = fmaf(2.f, k3, sm);
            y  = fmaf(0.1f / 6.0f, sm, y);
            y_[j] = y;
            a_[j] = fmaf(cg, y, a_[j]);
        }
    }
    ushort4 yb;
    yb.x = f2bf(a_[0]); yb.y = f2bf(a_[1]); yb.z = f2bf(a_[2]); yb.w = f2bf(a_[3]);
    *reinterpret_cast<ushort4*>(ytbf + base) = yb;
}

// ---------------- K2: GEMM2 (feature @ w2^T + b2), relu, max over n ----------------
// grid 4096: blockIdx = b*16 + colblock ; block = 4 waves, wave owns 16 cols
__global__ void __launch_bounds__(256) k_gemm2max(
    const unsigned short* __restrict__ featbf, const unsigned short* __restrict__ w2bf,
    const float* __restrict__ w2bias, float* __restrict__ x2max) {

    int b    = blockIdx.x >> 4;
    int cb   = blockIdx.x & 15;
    int wave = threadIdx.x >> 6, lane = threadIdx.x & 63;
    int col16 = lane & 15, krow = lane >> 4;
    int colbase = cb * 64 + wave * 16;

    bf16x8 bfr[8];
    const unsigned short* bp = w2bf + (size_t)(colbase + col16) * 256 + krow * 8;
#pragma unroll
    for (int k0 = 0; k0 < 8; ++k0) bfr[k0] = *reinterpret_cast<const bf16x8*>(bp + k0 * 32);

    const unsigned short* ap[7];
#pragma unroll
    for (int mt = 0; mt < 7; ++mt) {
        int r = b * 100 + mt * 16 + col16;
        if (r > BN_ROWS - 1) r = BN_ROWS - 1;   // clamp; masked in epilogue
        ap[mt] = featbf + (size_t)r * 256 + krow * 8;
    }
    f32x4 acc[7];
#pragma unroll
    for (int mt = 0; mt < 7; ++mt) acc[mt] = (f32x4){0.f, 0.f, 0.f, 0.f};

#pragma unroll
    for (int k0 = 0; k0 < 8; ++k0) {
        bf16x8 af[7];
#pragma unroll
        for (int mt = 0; mt < 7; ++mt) af[mt] = *reinterpret_cast<const bf16x8*>(ap[mt] + k0 * 32);
#pragma unroll
        for (int mt = 0; mt < 7; ++mt) acc[mt] = MFMA16(af[mt], bfr[k0], acc[mt]);
    }

    float bias = w2bias[colbase + col16];
    float m = 0.f;   // true max >= 0 because of relu over 100 valid rows
#pragma unroll
    for (int mt = 0; mt < 7; ++mt) {
#pragma unroll
        for (int r = 0; r < 4; ++r) {
            int n = mt * 16 + krow * 4 + r;
            float v = fmaxf(acc[mt][r] + bias, 0.f);
            if (n < 100) m = fmaxf(m, v);
        }
    }
    m = fmaxf(m, __shfl_xor(m, 16));
    m = fmaxf(m, __shfl_xor(m, 32));
    if (lane < 16) x2max[b * 1024 + colbase + lane] = m;
}

// ---------------- K2b: per-batch v_b = x2max_b @ w3a^T + b3 (f32) ----------------
__global__ void __launch_bounds__(128) k_vb(
    const float* __restrict__ x2max, const float* __restrict__ w3W,
    const float* __restrict__ w3b, float* __restrict__ v) {

    __shared__ float xs[1024];
    int b = blockIdx.x;
    for (int i = threadIdx.x; i < 1024; i += 128) xs[i] = x2max[b * 1024 + i];
    __syncthreads();

    int j = threadIdx.x;
    const float4* wr4 = reinterpret_cast<const float4*>(w3W + (size_t)j * 1280);
    const float4* xs4 = reinterpret_cast<const float4*>(xs);
    float s0 = 0.f, s1 = 0.f, s2 = 0.f, s3 = 0.f;
#pragma unroll 4
    for (int d = 0; d < 256; ++d) {
        float4 a = xs4[d];
        float4 w = wr4[d];
        s0 = fmaf(a.x, w.x, s0);
        s1 = fmaf(a.y, w.y, s1);
        s2 = fmaf(a.z, w.z, s2);
        s3 = fmaf(a.w, w.w, s3);
    }
    v[b * 128 + j] = w3b[j] + ((s0 + s1) + (s2 + s3));
}

// ---------------- K3: h3 = relu(v_b + yt @ w3b^T) ; out = h3 @ outW^T + outb ----------------
// grid 800: 32 rows per block; 4 waves, wave owns 32 cols (2 n-tiles)
__global__ void __launch_bounds__(256) k_final(
    const unsigned short* __restrict__ ytbf, const unsigned short* __restrict__ w3bbf,
    const float* __restrict__ vv, const float* __restrict__ outW,
    const float* __restrict__ outb, float* __restrict__ out) {

    __shared__ float h3s[32][132];
    int rbase = blockIdx.x * 32;
    int wave = threadIdx.x >> 6, lane = threadIdx.x & 63;
    int col16 = lane & 15, krow = lane >> 4;

    const unsigned short* ap0 = ytbf + (size_t)(rbase + col16) * 256 + krow * 8;
    const unsigned short* ap1 = ap0 + 16 * 256;
    const unsigned short* bp0 = w3bbf + (size_t)(wave * 32 + col16) * 256 + krow * 8;
    const unsigned short* bp1 = bp0 + 16 * 256;

    f32x4 a00 = {0.f,0.f,0.f,0.f}, a01 = {0.f,0.f,0.f,0.f};
    f32x4 a10 = {0.f,0.f,0.f,0.f}, a11 = {0.f,0.f,0.f,0.f};
#pragma unroll
    for (int k0 = 0; k0 < 8; ++k0) {
        bf16x8 A0 = *reinterpret_cast<const bf16x8*>(ap0 + k0 * 32);
        bf16x8 A1 = *reinterpret_cast<const bf16x8*>(ap1 + k0 * 32);
        bf16x8 B0 = *reinterpret_cast<const bf16x8*>(bp0 + k0 * 32);
        bf16x8 B1 = *reinterpret_cast<const bf16x8*>(bp1 + k0 * 32);
        a00 = MFMA16(A0, B0, a00);
        a01 = MFMA16(A0, B1, a01);
        a10 = MFMA16(A1, B0, a10);
        a11 = MFMA16(A1, B1, a11);
    }

#pragma unroll
    for (int mt = 0; mt < 2; ++mt) {
#pragma unroll
        for (int nt = 0; nt < 2; ++nt) {
            f32x4 acc = (mt == 0) ? ((nt == 0) ? a00 : a01) : ((nt == 0) ? a10 : a11);
#pragma unroll
            for (int r = 0; r < 4; ++r) {
                int rloc  = mt * 16 + krow * 4 + r;
                int rglob = rbase + rloc;
                int bb    = rglob / 100;
                int col   = wave * 32 + nt * 16 + col16;
                float h = acc[r] + vv[bb * 128 + col];
                h3s[rloc][col] = fmaxf(h, 0.f);
            }
        }
    }
    __syncthreads();

    int r  = threadIdx.x >> 3;   // 0..31
    int jg = threadIdx.x & 7;    // 0..7
    float p0 = 0.f, p1 = 0.f;
#pragma unroll
    for (int t = 0; t < 16; ++t) {
        int j = jg * 16 + t;
        float h = h3s[r][j];
        p0 = fmaf(h, outW[j], p0);
        p1 = fmaf(h, outW[128 + j], p1);
    }
    p0 += __shfl_xor(p0, 1); p0 += __shfl_xor(p0, 2); p0 += __shfl_xor(p0, 4);
    p1 += __shfl_xor(p1, 1); p1 += __shfl_xor(p1, 2); p1 += __shfl_xor(p1, 4);
    if (jg == 0) {
        int rg = rbase + r;
        out[rg * 2 + 0] = p0 + outb[0];
        out[rg * 2 + 1] = p1 + outb[1];
    }
}

extern "C" void kernel_launch(void* const* d_in, const int* in_sizes, int n_in,
                              void* d_out, int out_size, void* d_ws, size_t ws_size,
                              hipStream_t stream) {
    const float* x    = (const float*)d_in[0];
    const float* w1W  = (const float*)d_in[1];
    const float* w1b  = (const float*)d_in[2];
    const float* w2W  = (const float*)d_in[3];
    const float* w2b  = (const float*)d_in[4];
    const float* w3W  = (const float*)d_in[5];
    const float* w3b  = (const float*)d_in[6];
    const float* outW = (const float*)d_in[7];
    const float* outb = (const float*)d_in[8];
    const float* wp   = (const float*)d_in[9];
    float* out = (float*)d_out;

    char* ws = (char*)d_ws;
    unsigned short* featbf = (unsigned short*)(ws);                 // 25600*256 bf16 = 13,107,200 B
    unsigned short* ytbf   = (unsigned short*)(ws + 13107200);      // 13,107,200 B
    unsigned short* w2bf_  = (unsigned short*)(ws + 26214400);      // 1024*256 bf16 = 524,288 B
    unsigned short* w3bbf_ = (unsigned short*)(ws + 26738688);      // 128*256 bf16 = 65,536 B
    float* x2max           = (float*)(ws + 26804224);               // 256*1024 f32 = 1,048,576 B
    float* vv              = (float*)(ws + 27852800);               // 256*128 f32 = 131,072 B
    // total ws use: 27,983,872 B

    k_convert<<<1152, 256, 0, stream>>>(w2W, w3W, w2bf_, w3bbf_);
    k_feat_ode<<<6400, 256, 0, stream>>>(x, w1W, w1b, wp, featbf, ytbf);
    k_gemm2max<<<4096, 256, 0, stream>>>(featbf, w2bf_, w2b, x2max);
    k_vb<<<256, 128, 0, stream>>>(x2max, w3W, w3b, vv);
    k_final<<<800, 256, 0, stream>>>(ytbf, w3bbf_, vv, outW, outb, out);
}

// Round 2
// 156.644 us; speedup vs baseline: 1.5772x; 1.5772x over previous
//
#include <hip/hip_runtime.h>

typedef __bf16 bf16x8 __attribute__((ext_vector_type(8)));
typedef float f32x4 __attribute__((ext_vector_type(4)));

#define MFMA16(a, b, c) __builtin_amdgcn_mfma_f32_16x16x32_bf16((a), (b), (c), 0, 0, 0)

#define BN_ROWS 25600   // B*N
#define DH 256
#define INVPI 0.31830988618379067f

__device__ __forceinline__ unsigned short f2bf(float f) {
    unsigned int u = __float_as_uint(f);
    u = u + 0x7FFFu + ((u >> 16) & 1u);   // round-to-nearest-even
    return (unsigned short)(u >> 16);
}

// f(y) = -y + sin^2(y+gamma) = 0.5 - 0.5*cos(2y+2gamma) - y
// v_cos takes revolutions: rev = (y+gamma)/pi ; gp = gamma/pi precomputed
__device__ __forceinline__ float feval(float y, float gp) {
    float u = fmaf(y, INVPI, gp);
    float cc = __builtin_amdgcn_cosf(u);
    return fmaf(-0.5f, cc, 0.5f - y);
}

// ---------------- K0: convert weights to bf16 ----------------
__global__ void k_convert(const float* __restrict__ w2W, const float* __restrict__ w3W,
                          unsigned short* __restrict__ w2bf, unsigned short* __restrict__ w3bbf) {
    int i = blockIdx.x * 256 + threadIdx.x;   // grid covers 262144 + 32768 exactly
    if (i < 262144) {
        w2bf[i] = f2bf(w2W[i]);
    } else {
        int i2 = i - 262144;                  // < 32768
        int j = i2 >> 8, dk = i2 & 255;
        w3bbf[i2] = f2bf(w3W[j * 1280 + 1024 + dk]);  // yt-part of w3 (cols 1024..1279)
    }
}

// ---------------- K1: fused feature + RK4 ODE + pooled interp ----------------
__global__ void __launch_bounds__(256) k_feat_ode(
    const float* __restrict__ x, const float* __restrict__ w1W, const float* __restrict__ w1b,
    const float* __restrict__ wp,
    unsigned short* __restrict__ featbf, unsigned short* __restrict__ ytbf) {

    // pooling coefficients c[g]: softmax(wp) folded through fixed-grid linear interp
    float c[21];
#pragma unroll
    for (int g = 0; g < 21; ++g) c[g] = 0.f;
    {
        float wv[10];
#pragma unroll
        for (int t = 0; t < 10; ++t) wv[t] = wp[t];
        float m = wv[0];
#pragma unroll
        for (int t = 1; t < 10; ++t) m = fmaxf(m, wv[t]);
        float s = 0.f;
#pragma unroll
        for (int t = 0; t < 10; ++t) { wv[t] = __expf(wv[t] - m); s += wv[t]; }
        float inv = 1.f / s;
        const int   idxs[10]  = {0, 2, 4, 6, 8, 11, 13, 15, 17, 19};
        const float fracs[10] = {0.f, 0.22222222f, 0.44444445f, 0.6666667f, 0.8888889f,
                                 0.11111111f, 0.33333334f, 0.5555556f, 0.7777778f, 1.0f};
#pragma unroll
        for (int t = 0; t < 10; ++t) {
            float w = wv[t] * inv;
            c[idxs[t]]     += w * (1.f - fracs[t]);
            c[idxs[t] + 1] += w * fracs[t];
        }
    }

    int tid  = blockIdx.x * 256 + threadIdx.x;    // 1,638,400 threads exactly
    int base = tid * 4;
    int row  = base >> 8;        // 0..25599
    int d0   = base & 255;

    float x0 = x[row * 3 + 0], x1 = x[row * 3 + 1], x2v = x[row * 3 + 2];

    float g_[4], y_[4], a_[4], gp[4];
#pragma unroll
    for (int j = 0; j < 4; ++j) {
        const float* wr = w1W + (d0 + j) * 3;
        float f = fmaf(x0, wr[0], fmaf(x1, wr[1], fmaf(x2v, wr[2], w1b[d0 + j])));
        f = fmaxf(f, 0.f);
        g_[j] = f;
        gp[j] = f * INVPI;
        y_[j] = 0.f;
        a_[j] = 0.f;
    }
    ushort4 fb;
    fb.x = f2bf(g_[0]); fb.y = f2bf(g_[1]); fb.z = f2bf(g_[2]); fb.w = f2bf(g_[3]);
    *reinterpret_cast<ushort4*>(featbf + base) = fb;

#pragma unroll
    for (int st = 0; st < 20; ++st) {
        float cg = c[st + 1];
#pragma unroll
        for (int j = 0; j < 4; ++j) {
            float y  = y_[j];
            float k1 = feval(y, gp[j]);
            float k2 = feval(fmaf(0.05f, k1, y), gp[j]);
            float k3 = feval(fmaf(0.05f, k2, y), gp[j]);
            float k4 = feval(fmaf(0.1f,  k3, y), gp[j]);
            float sm = k1 + k4;
            sm = fmaf(2.f, k2, sm);
            sm = fmaf(2.f, k3, sm);
            y  = fmaf(0.1f / 6.0f, sm, y);
            y_[j] = y;
            a_[j] = fmaf(cg, y, a_[j]);
        }
    }
    ushort4 yb;
    yb.x = f2bf(a_[0]); yb.y = f2bf(a_[1]); yb.z = f2bf(a_[2]); yb.w = f2bf(a_[3]);
    *reinterpret_cast<ushort4*>(ytbf + base) = yb;
}

// ---------------- K2: GEMM2 (feature @ w2^T + b2), relu, max over n ----------------
// 1024 blocks = 256 batches x 4 col-quarters, XCD-chunked.
// Block stages feature[b] (112x256 bf16, zero-padded, XOR-swizzled) in LDS once;
// 4 waves x 64 cols each; B streamed from global (L2-resident per XCD) w/ prefetch.
__global__ void __launch_bounds__(256, 2) k_gemm2max(
    const unsigned short* __restrict__ featbf, const unsigned short* __restrict__ w2bf,
    const float* __restrict__ w2bias, float* __restrict__ x2max) {

    __shared__ unsigned short As[112 * 256];   // 57344 B

    int p = blockIdx.x;
    int xcd = p & 7, slot = p >> 3;
    int b = xcd * 32 + (slot >> 2);    // batches chunked 32-per-XCD
    int q = slot & 3;                  // col quarter (256 cols)

    // ---- stage A: 112 rows x 512B, rows >=100 zeroed; byte ^= (row&7)<<4 swizzle ----
    {
        const unsigned short* src = featbf + (size_t)b * 25600;  // 100*256
        int t = threadIdx.x;
#pragma unroll
        for (int it = 0; it < 14; ++it) {
            int i = t + it * 256;            // chunk index, 0..3583
            int row = i >> 5, ch = i & 31;   // 32 x 16B chunks per row
            int byte = row * 512 + ((ch * 16) ^ ((row & 7) << 4));
            bf16x8 v = {};
            if (row < 100) v = *reinterpret_cast<const bf16x8*>(src + row * 256 + ch * 8);
            *reinterpret_cast<bf16x8*>((char*)As + byte) = v;
        }
    }
    __syncthreads();

    int wave = threadIdx.x >> 6, lane = threadIdx.x & 63;
    int col16 = lane & 15, krow = lane >> 4;
    int colbase = q * 256 + wave * 64;
    int sw = (col16 & 7) << 4;

    const unsigned short* bp = w2bf + (size_t)(colbase + col16) * 256 + krow * 8;

    f32x4 acc[7][4];
#pragma unroll
    for (int mt = 0; mt < 7; ++mt)
#pragma unroll
        for (int ct = 0; ct < 4; ++ct) acc[mt][ct] = (f32x4){0.f, 0.f, 0.f, 0.f};

    bf16x8 Bcur[4], Bnxt[4];
#pragma unroll
    for (int ct = 0; ct < 4; ++ct)
        Bcur[ct] = *reinterpret_cast<const bf16x8*>(bp + ct * 4096);

    const char* Ab = (const char*)As;
#pragma unroll
    for (int k0 = 0; k0 < 8; ++k0) {
        int off = (k0 * 64 + krow * 16) ^ sw;
        bf16x8 Af[7];
#pragma unroll
        for (int mt = 0; mt < 7; ++mt)
            Af[mt] = *reinterpret_cast<const bf16x8*>(Ab + (mt * 16 + col16) * 512 + off);
        if (k0 < 7) {
#pragma unroll
            for (int ct = 0; ct < 4; ++ct)
                Bnxt[ct] = *reinterpret_cast<const bf16x8*>(bp + ct * 4096 + (k0 + 1) * 32);
        }
#pragma unroll
        for (int mt = 0; mt < 7; ++mt)
#pragma unroll
            for (int ct = 0; ct < 4; ++ct)
                acc[mt][ct] = MFMA16(Af[mt], Bcur[ct], acc[mt][ct]);
#pragma unroll
        for (int ct = 0; ct < 4; ++ct) Bcur[ct] = Bnxt[ct];
    }

    // ---- epilogue: relu(acc+bias), max over valid rows n<100 ----
    float bias[4], m[4];
#pragma unroll
    for (int ct = 0; ct < 4; ++ct) {
        bias[ct] = w2bias[colbase + ct * 16 + col16];
        m[ct] = 0.f;   // true max >= 0 (relu over 100 valid rows)
    }
#pragma unroll
    for (int mt = 0; mt < 7; ++mt) {
#pragma unroll
        for (int r = 0; r < 4; ++r) {
            int n = mt * 16 + krow * 4 + r;
            bool valid = n < 100;
#pragma unroll
            for (int ct = 0; ct < 4; ++ct) {
                float v = fmaxf(acc[mt][ct][r] + bias[ct], 0.f);
                if (valid) m[ct] = fmaxf(m[ct], v);
            }
        }
    }
#pragma unroll
    for (int ct = 0; ct < 4; ++ct) {
        m[ct] = fmaxf(m[ct], __shfl_xor(m[ct], 16));
        m[ct] = fmaxf(m[ct], __shfl_xor(m[ct], 32));
    }
    if (lane < 16) {
#pragma unroll
        for (int ct = 0; ct < 4; ++ct)
            x2max[b * 1024 + colbase + ct * 16 + lane] = m[ct];
    }
}

// ---------------- K2b: per-batch v_b = x2max_b @ w3a^T + b3 (f32) ----------------
__global__ void __launch_bounds__(128) k_vb(
    const float* __restrict__ x2max, const float* __restrict__ w3W,
    const float* __restrict__ w3b, float* __restrict__ v) {

    __shared__ float xs[1024];
    int b = blockIdx.x;
    for (int i = threadIdx.x; i < 1024; i += 128) xs[i] = x2max[b * 1024 + i];
    __syncthreads();

    int j = threadIdx.x;
    const float4* wr4 = reinterpret_cast<const float4*>(w3W + (size_t)j * 1280);
    const float4* xs4 = reinterpret_cast<const float4*>(xs);
    float s0 = 0.f, s1 = 0.f, s2 = 0.f, s3 = 0.f;
#pragma unroll 4
    for (int d = 0; d < 256; ++d) {
        float4 a = xs4[d];
        float4 w = wr4[d];
        s0 = fmaf(a.x, w.x, s0);
        s1 = fmaf(a.y, w.y, s1);
        s2 = fmaf(a.z, w.z, s2);
        s3 = fmaf(a.w, w.w, s3);
    }
    v[b * 128 + j] = w3b[j] + ((s0 + s1) + (s2 + s3));
}

// ---------------- K3: h3 = relu(v_b + yt @ w3b^T) ; out = h3 @ outW^T + outb ----------------
// grid 800: 32 rows per block; 4 waves, wave owns 32 cols (2 n-tiles)
__global__ void __launch_bounds__(256) k_final(
    const unsigned short* __restrict__ ytbf, const unsigned short* __restrict__ w3bbf,
    const float* __restrict__ vv, const float* __restrict__ outW,
    const float* __restrict__ outb, float* __restrict__ out) {

    __shared__ float h3s[32][132];
    int rbase = blockIdx.x * 32;
    int wave = threadIdx.x >> 6, lane = threadIdx.x & 63;
    int col16 = lane & 15, krow = lane >> 4;

    const unsigned short* ap0 = ytbf + (size_t)(rbase + col16) * 256 + krow * 8;
    const unsigned short* ap1 = ap0 + 16 * 256;
    const unsigned short* bp0 = w3bbf + (size_t)(wave * 32 + col16) * 256 + krow * 8;
    const unsigned short* bp1 = bp0 + 16 * 256;

    f32x4 a00 = {0.f,0.f,0.f,0.f}, a01 = {0.f,0.f,0.f,0.f};
    f32x4 a10 = {0.f,0.f,0.f,0.f}, a11 = {0.f,0.f,0.f,0.f};
#pragma unroll
    for (int k0 = 0; k0 < 8; ++k0) {
        bf16x8 A0 = *reinterpret_cast<const bf16x8*>(ap0 + k0 * 32);
        bf16x8 A1 = *reinterpret_cast<const bf16x8*>(ap1 + k0 * 32);
        bf16x8 B0 = *reinterpret_cast<const bf16x8*>(bp0 + k0 * 32);
        bf16x8 B1 = *reinterpret_cast<const bf16x8*>(bp1 + k0 * 32);
        a00 = MFMA16(A0, B0, a00);
        a01 = MFMA16(A0, B1, a01);
        a10 = MFMA16(A1, B0, a10);
        a11 = MFMA16(A1, B1, a11);
    }

#pragma unroll
    for (int mt = 0; mt < 2; ++mt) {
#pragma unroll
        for (int nt = 0; nt < 2; ++nt) {
            f32x4 acc = (mt == 0) ? ((nt == 0) ? a00 : a01) : ((nt == 0) ? a10 : a11);
#pragma unroll
            for (int r = 0; r < 4; ++r) {
                int rloc  = mt * 16 + krow * 4 + r;
                int rglob = rbase + rloc;
                int bb    = rglob / 100;
                int col   = wave * 32 + nt * 16 + col16;
                float h = acc[r] + vv[bb * 128 + col];
                h3s[rloc][col] = fmaxf(h, 0.f);
            }
        }
    }
    __syncthreads();

    int r  = threadIdx.x >> 3;   // 0..31
    int jg = threadIdx.x & 7;    // 0..7
    float p0 = 0.f, p1 = 0.f;
#pragma unroll
    for (int t = 0; t < 16; ++t) {
        int j = jg * 16 + t;
        float h = h3s[r][j];
        p0 = fmaf(h, outW[j], p0);
        p1 = fmaf(h, outW[128 + j], p1);
    }
    p0 += __shfl_xor(p0, 1); p0 += __shfl_xor(p0, 2); p0 += __shfl_xor(p0, 4);
    p1 += __shfl_xor(p1, 1); p1 += __shfl_xor(p1, 2); p1 += __shfl_xor(p1, 4);
    if (jg == 0) {
        int rg = rbase + r;
        out[rg * 2 + 0] = p0 + outb[0];
        out[rg * 2 + 1] = p1 + outb[1];
    }
}

extern "C" void kernel_launch(void* const* d_in, const int* in_sizes, int n_in,
                              void* d_out, int out_size, void* d_ws, size_t ws_size,
                              hipStream_t stream) {
    const float* x    = (const float*)d_in[0];
    const float* w1W  = (const float*)d_in[1];
    const float* w1b  = (const float*)d_in[2];
    const float* w2W  = (const float*)d_in[3];
    const float* w2b  = (const float*)d_in[4];
    const float* w3W  = (const float*)d_in[5];
    const float* w3b  = (const float*)d_in[6];
    const float* outW = (const float*)d_in[7];
    const float* outb = (const float*)d_in[8];
    const float* wp   = (const float*)d_in[9];
    float* out = (float*)d_out;

    char* ws = (char*)d_ws;
    unsigned short* featbf = (unsigned short*)(ws);                 // 25600*256 bf16 = 13,107,200 B
    unsigned short* ytbf   = (unsigned short*)(ws + 13107200);      // 13,107,200 B
    unsigned short* w2bf_  = (unsigned short*)(ws + 26214400);      // 1024*256 bf16 = 524,288 B
    unsigned short* w3bbf_ = (unsigned short*)(ws + 26738688);      // 128*256 bf16 = 65,536 B
    float* x2max           = (float*)(ws + 26804224);               // 256*1024 f32 = 1,048,576 B
    float* vv              = (float*)(ws + 27852800);               // 256*128 f32 = 131,072 B
    // total ws use: 27,983,872 B

    k_convert<<<1152, 256, 0, stream>>>(w2W, w3W, w2bf_, w3bbf_);
    k_feat_ode<<<6400, 256, 0, stream>>>(x, w1W, w1b, wp, featbf, ytbf);
    k_gemm2max<<<1024, 256, 0, stream>>>(featbf, w2bf_, w2b, x2max);
    k_vb<<<256, 128, 0, stream>>>(x2max, w3W, w3b, vv);
    k_final<<<800, 256, 0, stream>>>(ytbf, w3bbf_, vv, outW, outb, out);
}

// Round 3
// 90.682 us; speedup vs baseline: 2.7245x; 1.7274x over previous
//
#include <hip/hip_runtime.h>

typedef __bf16 bf16x8 __attribute__((ext_vector_type(8)));
typedef float f32x4 __attribute__((ext_vector_type(4)));
typedef unsigned short u16x8 __attribute__((ext_vector_type(8)));

#define MFMA16(a, b, c) __builtin_amdgcn_mfma_f32_16x16x32_bf16((a), (b), (c), 0, 0, 0)

#define BN_ROWS 25600   // B*N
#define INVPI 0.31830988618379067f
#define TBL_N 4096
#define TBL_SCALE 409.6f          // TBL_N / gamma_range(10)
#define TBL_STEP (10.f / 4096.f)

__device__ __forceinline__ unsigned short f2bf(float f) {
    unsigned int u = __float_as_uint(f);
    u = u + 0x7FFFu + ((u >> 16) & 1u);   // round-to-nearest-even
    return (unsigned short)(u >> 16);
}

// f(y) = -y + sin^2(y+gamma) = 0.5 - 0.5*cos(2y+2gamma) - y
// v_cos takes revolutions: rev = (y+gamma)/pi ; gp = gamma/pi precomputed
__device__ __forceinline__ float feval(float y, float gp) {
    float u = fmaf(y, INVPI, gp);
    float cc = __builtin_amdgcn_cosf(u);
    return fmaf(-0.5f, cc, 0.5f - y);
}

// ---------------- K0: convert weights to bf16 + build yt(gamma) table ----------------
// blocks 0..1151: weight convert; blocks 1152..1167: 4096-entry ODE table
__global__ void k_prep(const float* __restrict__ w2W, const float* __restrict__ w3W,
                       const float* __restrict__ wp,
                       unsigned short* __restrict__ w2bf, unsigned short* __restrict__ w3bbf,
                       float* __restrict__ tbl) {
    if (blockIdx.x < 1152) {
        int i = blockIdx.x * 256 + threadIdx.x;
        if (i < 262144) {
            w2bf[i] = f2bf(w2W[i]);
        } else {
            int i2 = i - 262144;                  // < 32768
            int j = i2 >> 8, dk = i2 & 255;
            w3bbf[i2] = f2bf(w3W[j * 1280 + 1024 + dk]);  // yt-part of w3 (cols 1024..1279)
        }
        return;
    }

    // ---- table build: exact 20-step RK4 at gamma = gid * TBL_STEP ----
    int gid = (blockIdx.x - 1152) * 256 + threadIdx.x;   // 0..4095 exactly (16 blocks)

    // pooling coefficients c[g]: softmax(wp) folded through fixed-grid linear interp
    float c[21];
#pragma unroll
    for (int g = 0; g < 21; ++g) c[g] = 0.f;
    {
        float wv[10];
#pragma unroll
        for (int t = 0; t < 10; ++t) wv[t] = wp[t];
        float m = wv[0];
#pragma unroll
        for (int t = 1; t < 10; ++t) m = fmaxf(m, wv[t]);
        float s = 0.f;
#pragma unroll
        for (int t = 0; t < 10; ++t) { wv[t] = __expf(wv[t] - m); s += wv[t]; }
        float inv = 1.f / s;
        const int   idxs[10]  = {0, 2, 4, 6, 8, 11, 13, 15, 17, 19};
        const float fracs[10] = {0.f, 0.22222222f, 0.44444445f, 0.6666667f, 0.8888889f,
                                 0.11111111f, 0.33333334f, 0.5555556f, 0.7777778f, 1.0f};
#pragma unroll
        for (int t = 0; t < 10; ++t) {
            float w = wv[t] * inv;
            c[idxs[t]]     += w * (1.f - fracs[t]);
            c[idxs[t] + 1] += w * fracs[t];
        }
    }

    float gamma = gid * TBL_STEP;
    float gp = gamma * INVPI;
    float y = 0.f, acc = 0.f;
#pragma unroll
    for (int st = 0; st < 20; ++st) {
        float k1 = feval(y, gp);
        float k2 = feval(fmaf(0.05f, k1, y), gp);
        float k3 = feval(fmaf(0.05f, k2, y), gp);
        float k4 = feval(fmaf(0.1f,  k3, y), gp);
        float sm = k1 + k4;
        sm = fmaf(2.f, k2, sm);
        sm = fmaf(2.f, k3, sm);
        y  = fmaf(0.1f / 6.0f, sm, y);
        acc = fmaf(c[st + 1], y, acc);
    }
    tbl[gid] = acc;
}

// ---------------- K1: feature = relu(x@w1^T+b1) ; yt = lerp(tbl, feature) ----------------
// 3200 blocks x 256 threads, 8 elements (one 8-wide d-slice of one row) per thread
__global__ void __launch_bounds__(256) k_feat(
    const float* __restrict__ x, const float* __restrict__ w1W, const float* __restrict__ w1b,
    const float* __restrict__ tbl,
    unsigned short* __restrict__ featbf, unsigned short* __restrict__ ytbf) {

    __shared__ float tl[TBL_N];
    {
        const float4* g4 = reinterpret_cast<const float4*>(tbl);
        float4* l4 = reinterpret_cast<float4*>(tl);
#pragma unroll
        for (int r = 0; r < 4; ++r) l4[r * 256 + threadIdx.x] = g4[r * 256 + threadIdx.x];
    }
    __syncthreads();

    int tid  = blockIdx.x * 256 + threadIdx.x;    // 819,200 threads
    int base = tid * 8;
    int row  = base >> 8;        // 0..25599
    int d0   = base & 255;       // multiple of 8

    float x0 = x[row * 3 + 0], x1 = x[row * 3 + 1], x2v = x[row * 3 + 2];

    float wreg[24];
    {
        const float4* w4 = reinterpret_cast<const float4*>(w1W + d0 * 3);
#pragma unroll
        for (int q = 0; q < 6; ++q) *reinterpret_cast<float4*>(&wreg[q * 4]) = w4[q];
    }
    float bb[8];
    {
        const float4* b4 = reinterpret_cast<const float4*>(w1b + d0);
        *reinterpret_cast<float4*>(&bb[0]) = b4[0];
        *reinterpret_cast<float4*>(&bb[4]) = b4[1];
    }

    u16x8 fbv, ybv;
#pragma unroll
    for (int j = 0; j < 8; ++j) {
        float g = fmaf(x0, wreg[j * 3], fmaf(x1, wreg[j * 3 + 1], fmaf(x2v, wreg[j * 3 + 2], bb[j])));
        g = fmaxf(g, 0.f);
        fbv[j] = f2bf(g);
        float t = g * TBL_SCALE;
        int i = (int)t;
        i = (i > TBL_N - 2) ? (TBL_N - 2) : i;
        float fr = t - (float)i;
        float a = tl[i], b = tl[i + 1];
        ybv[j] = f2bf(fmaf(fr, b - a, a));
    }
    *reinterpret_cast<u16x8*>(featbf + base) = fbv;
    *reinterpret_cast<u16x8*>(ytbf + base) = ybv;
}

// ---------------- K2: GEMM2 (feature @ w2^T + b2), relu, max over n ----------------
// 1024 blocks = 256 batches x 4 col-quarters, XCD-chunked.
// Block stages feature[b] (112x256 bf16, zero-padded, XOR-swizzled) in LDS once;
// 4 waves x 64 cols each; B streamed from global (L2-resident per XCD) w/ prefetch.
__global__ void __launch_bounds__(256, 2) k_gemm2max(
    const unsigned short* __restrict__ featbf, const unsigned short* __restrict__ w2bf,
    const float* __restrict__ w2bias, float* __restrict__ x2max) {

    __shared__ unsigned short As[112 * 256];   // 57344 B

    int p = blockIdx.x;
    int xcd = p & 7, slot = p >> 3;
    int b = xcd * 32 + (slot >> 2);    // batches chunked 32-per-XCD
    int q = slot & 3;                  // col quarter (256 cols)

    // ---- stage A: 112 rows x 512B, rows >=100 zeroed; byte ^= (row&7)<<4 swizzle ----
    {
        const unsigned short* src = featbf + (size_t)b * 25600;  // 100*256
        int t = threadIdx.x;
#pragma unroll
        for (int it = 0; it < 14; ++it) {
            int i = t + it * 256;            // chunk index, 0..3583
            int row = i >> 5, ch = i & 31;   // 32 x 16B chunks per row
            int byte = row * 512 + ((ch * 16) ^ ((row & 7) << 4));
            bf16x8 v = {};
            if (row < 100) v = *reinterpret_cast<const bf16x8*>(src + row * 256 + ch * 8);
            *reinterpret_cast<bf16x8*>((char*)As + byte) = v;
        }
    }
    __syncthreads();

    int wave = threadIdx.x >> 6, lane = threadIdx.x & 63;
    int col16 = lane & 15, krow = lane >> 4;
    int colbase = q * 256 + wave * 64;
    int sw = (col16 & 7) << 4;

    const unsigned short* bp = w2bf + (size_t)(colbase + col16) * 256 + krow * 8;

    f32x4 acc[7][4];
#pragma unroll
    for (int mt = 0; mt < 7; ++mt)
#pragma unroll
        for (int ct = 0; ct < 4; ++ct) acc[mt][ct] = (f32x4){0.f, 0.f, 0.f, 0.f};

    bf16x8 Bcur[4], Bnxt[4];
#pragma unroll
    for (int ct = 0; ct < 4; ++ct)
        Bcur[ct] = *reinterpret_cast<const bf16x8*>(bp + ct * 4096);

    const char* Ab = (const char*)As;
#pragma unroll
    for (int k0 = 0; k0 < 8; ++k0) {
        int off = (k0 * 64 + krow * 16) ^ sw;
        bf16x8 Af[7];
#pragma unroll
        for (int mt = 0; mt < 7; ++mt)
            Af[mt] = *reinterpret_cast<const bf16x8*>(Ab + (mt * 16 + col16) * 512 + off);
        if (k0 < 7) {
#pragma unroll
            for (int ct = 0; ct < 4; ++ct)
                Bnxt[ct] = *reinterpret_cast<const bf16x8*>(bp + ct * 4096 + (k0 + 1) * 32);
        }
#pragma unroll
        for (int mt = 0; mt < 7; ++mt)
#pragma unroll
            for (int ct = 0; ct < 4; ++ct)
                acc[mt][ct] = MFMA16(Af[mt], Bcur[ct], acc[mt][ct]);
#pragma unroll
        for (int ct = 0; ct < 4; ++ct) Bcur[ct] = Bnxt[ct];
    }

    // ---- epilogue: relu(acc+bias), max over valid rows n<100 ----
    float bias[4], m[4];
#pragma unroll
    for (int ct = 0; ct < 4; ++ct) {
        bias[ct] = w2bias[colbase + ct * 16 + col16];
        m[ct] = 0.f;   // true max >= 0 (relu over 100 valid rows)
    }
#pragma unroll
    for (int mt = 0; mt < 7; ++mt) {
#pragma unroll
        for (int r = 0; r < 4; ++r) {
            int n = mt * 16 + krow * 4 + r;
            bool valid = n < 100;
#pragma unroll
            for (int ct = 0; ct < 4; ++ct) {
                float v = fmaxf(acc[mt][ct][r] + bias[ct], 0.f);
                if (valid) m[ct] = fmaxf(m[ct], v);
            }
        }
    }
#pragma unroll
    for (int ct = 0; ct < 4; ++ct) {
        m[ct] = fmaxf(m[ct], __shfl_xor(m[ct], 16));
        m[ct] = fmaxf(m[ct], __shfl_xor(m[ct], 32));
    }
    if (lane < 16) {
#pragma unroll
        for (int ct = 0; ct < 4; ++ct)
            x2max[b * 1024 + colbase + ct * 16 + lane] = m[ct];
    }
}

// ---------------- K2b: per-batch v_b = x2max_b @ w3a^T + b3 (f32) ----------------
__global__ void __launch_bounds__(128) k_vb(
    const float* __restrict__ x2max, const float* __restrict__ w3W,
    const float* __restrict__ w3b, float* __restrict__ v) {

    __shared__ float xs[1024];
    int b = blockIdx.x;
    for (int i = threadIdx.x; i < 1024; i += 128) xs[i] = x2max[b * 1024 + i];
    __syncthreads();

    int j = threadIdx.x;
    const float4* wr4 = reinterpret_cast<const float4*>(w3W + (size_t)j * 1280);
    const float4* xs4 = reinterpret_cast<const float4*>(xs);
    float s0 = 0.f, s1 = 0.f, s2 = 0.f, s3 = 0.f;
#pragma unroll 4
    for (int d = 0; d < 256; ++d) {
        float4 a = xs4[d];
        float4 w = wr4[d];
        s0 = fmaf(a.x, w.x, s0);
        s1 = fmaf(a.y, w.y, s1);
        s2 = fmaf(a.z, w.z, s2);
        s3 = fmaf(a.w, w.w, s3);
    }
    v[b * 128 + j] = w3b[j] + ((s0 + s1) + (s2 + s3));
}

// ---------------- K3: h3 = relu(v_b + yt @ w3b^T) ; out = h3 @ outW^T + outb ----------------
// grid 800: 32 rows per block; 4 waves, wave owns 32 cols (2 n-tiles)
__global__ void __launch_bounds__(256) k_final(
    const unsigned short* __restrict__ ytbf, const unsigned short* __restrict__ w3bbf,
    const float* __restrict__ vv, const float* __restrict__ outW,
    const float* __restrict__ outb, float* __restrict__ out) {

    __shared__ float h3s[32][132];
    int rbase = blockIdx.x * 32;
    int wave = threadIdx.x >> 6, lane = threadIdx.x & 63;
    int col16 = lane & 15, krow = lane >> 4;

    const unsigned short* ap0 = ytbf + (size_t)(rbase + col16) * 256 + krow * 8;
    const unsigned short* ap1 = ap0 + 16 * 256;
    const unsigned short* bp0 = w3bbf + (size_t)(wave * 32 + col16) * 256 + krow * 8;
    const unsigned short* bp1 = bp0 + 16 * 256;

    f32x4 a00 = {0.f,0.f,0.f,0.f}, a01 = {0.f,0.f,0.f,0.f};
    f32x4 a10 = {0.f,0.f,0.f,0.f}, a11 = {0.f,0.f,0.f,0.f};
#pragma unroll
    for (int k0 = 0; k0 < 8; ++k0) {
        bf16x8 A0 = *reinterpret_cast<const bf16x8*>(ap0 + k0 * 32);
        bf16x8 A1 = *reinterpret_cast<const bf16x8*>(ap1 + k0 * 32);
        bf16x8 B0 = *reinterpret_cast<const bf16x8*>(bp0 + k0 * 32);
        bf16x8 B1 = *reinterpret_cast<const bf16x8*>(bp1 + k0 * 32);
        a00 = MFMA16(A0, B0, a00);
        a01 = MFMA16(A0, B1, a01);
        a10 = MFMA16(A1, B0, a10);
        a11 = MFMA16(A1, B1, a11);
    }

#pragma unroll
    for (int mt = 0; mt < 2; ++mt) {
#pragma unroll
        for (int nt = 0; nt < 2; ++nt) {
            f32x4 acc = (mt == 0) ? ((nt == 0) ? a00 : a01) : ((nt == 0) ? a10 : a11);
#pragma unroll
            for (int r = 0; r < 4; ++r) {
                int rloc  = mt * 16 + krow * 4 + r;
                int rglob = rbase + rloc;
                int bb    = rglob / 100;
                int col   = wave * 32 + nt * 16 + col16;
                float h = acc[r] + vv[bb * 128 + col];
                h3s[rloc][col] = fmaxf(h, 0.f);
            }
        }
    }
    __syncthreads();

    int r  = threadIdx.x >> 3;   // 0..31
    int jg = threadIdx.x & 7;    // 0..7
    float p0 = 0.f, p1 = 0.f;
#pragma unroll
    for (int t = 0; t < 16; ++t) {
        int j = jg * 16 + t;
        float h = h3s[r][j];
        p0 = fmaf(h, outW[j], p0);
        p1 = fmaf(h, outW[128 + j], p1);
    }
    p0 += __shfl_xor(p0, 1); p0 += __shfl_xor(p0, 2); p0 += __shfl_xor(p0, 4);
    p1 += __shfl_xor(p1, 1); p1 += __shfl_xor(p1, 2); p1 += __shfl_xor(p1, 4);
    if (jg == 0) {
        int rg = rbase + r;
        out[rg * 2 + 0] = p0 + outb[0];
        out[rg * 2 + 1] = p1 + outb[1];
    }
}

extern "C" void kernel_launch(void* const* d_in, const int* in_sizes, int n_in,
                              void* d_out, int out_size, void* d_ws, size_t ws_size,
                              hipStream_t stream) {
    const float* x    = (const float*)d_in[0];
    const float* w1W  = (const float*)d_in[1];
    const float* w1b  = (const float*)d_in[2];
    const float* w2W  = (const float*)d_in[3];
    const float* w2b  = (const float*)d_in[4];
    const float* w3W  = (const float*)d_in[5];
    const float* w3b  = (const float*)d_in[6];
    const float* outW = (const float*)d_in[7];
    const float* outb = (const float*)d_in[8];
    const float* wp   = (const float*)d_in[9];
    float* out = (float*)d_out;

    char* ws = (char*)d_ws;
    unsigned short* featbf = (unsigned short*)(ws);                 // 25600*256 bf16 = 13,107,200 B
    unsigned short* ytbf   = (unsigned short*)(ws + 13107200);      // 13,107,200 B
    unsigned short* w2bf_  = (unsigned short*)(ws + 26214400);      // 1024*256 bf16 = 524,288 B
    unsigned short* w3bbf_ = (unsigned short*)(ws + 26738688);      // 128*256 bf16 = 65,536 B
    float* x2max           = (float*)(ws + 26804224);               // 256*1024 f32 = 1,048,576 B
    float* vv              = (float*)(ws + 27852800);               // 256*128 f32 = 131,072 B
    // tbl (16 KB) aliases the TAIL of the x2max region: written by k_prep, read by
    // k_feat, then overwritten by k_gemm2max (which runs strictly after k_feat on
    // the same stream). Keeps total ws use at 27,983,872 B.
    float* tbl             = (float*)(ws + 27836416);

    k_prep<<<1168, 256, 0, stream>>>(w2W, w3W, wp, w2bf_, w3bbf_, tbl);
    k_feat<<<3200, 256, 0, stream>>>(x, w1W, w1b, tbl, featbf, ytbf);
    k_gemm2max<<<1024, 256, 0, stream>>>(featbf, w2bf_, w2b, x2max);
    k_vb<<<256, 128, 0, stream>>>(x2max, w3W, w3b, vv);
    k_final<<<800, 256, 0, stream>>>(ytbf, w3bbf_, vv, outW, outb, out);
}

// Round 4
// 70.369 us; speedup vs baseline: 3.5110x; 1.2887x over previous
//
#include <hip/hip_runtime.h>

typedef __bf16 bf16x8 __attribute__((ext_vector_type(8)));
typedef float f32x4 __attribute__((ext_vector_type(4)));
typedef unsigned short u16x8 __attribute__((ext_vector_type(8)));

#define MFMA16(a, b, c) __builtin_amdgcn_mfma_f32_16x16x32_bf16((a), (b), (c), 0, 0, 0)

#define BN_ROWS 25600   // B*N
#define INVPI 0.31830988618379067f
#define TBL_N 4096
#define TBL_SCALE 409.6f          // TBL_N / gamma_range(10)
#define TBL_STEP (10.f / 4096.f)

__device__ __forceinline__ unsigned short f2bf(float f) {
    unsigned int u = __float_as_uint(f);
    u = u + 0x7FFFu + ((u >> 16) & 1u);   // round-to-nearest-even
    return (unsigned short)(u >> 16);
}

// f(y) = -y + sin^2(y+gamma) = 0.5 - 0.5*cos(2y+2gamma) - y
// v_cos takes revolutions: rev = (y+gamma)/pi ; gp = gamma/pi precomputed
__device__ __forceinline__ float feval(float y, float gp) {
    float u = fmaf(y, INVPI, gp);
    float cc = __builtin_amdgcn_cosf(u);
    return fmaf(-0.5f, cc, 0.5f - y);
}

// ---------------- K0: prep — weight converts, ODE table, w3a transpose ----------------
// blocks   0..127 : w2 -> bf16 (8 elem/thread)
// blocks 128..143 : w3 yt-part -> bf16 (8 elem/thread)
// blocks 144..159 : 4096-entry ODE table
// blocks 160..671 : w3a transpose to [1024][128] f32
__global__ void k_prep(const float* __restrict__ w2W, const float* __restrict__ w3W,
                       const float* __restrict__ wp,
                       unsigned short* __restrict__ w2bf, unsigned short* __restrict__ w3bbf,
                       float* __restrict__ tbl, float* __restrict__ w3aT) {
    int blk = blockIdx.x;
    if (blk < 128) {
        int i = (blk * 256 + threadIdx.x) * 8;
        const float4* s4 = reinterpret_cast<const float4*>(w2W + i);
        float4 a = s4[0], b = s4[1];
        u16x8 o;
        o[0] = f2bf(a.x); o[1] = f2bf(a.y); o[2] = f2bf(a.z); o[3] = f2bf(a.w);
        o[4] = f2bf(b.x); o[5] = f2bf(b.y); o[6] = f2bf(b.z); o[7] = f2bf(b.w);
        *reinterpret_cast<u16x8*>(w2bf + i) = o;
        return;
    }
    if (blk < 144) {
        int idx = ((blk - 128) * 256 + threadIdx.x) * 8;   // < 32768, multiple of 8
        int j = idx >> 8, dk = idx & 255;
        const float4* s4 = reinterpret_cast<const float4*>(w3W + j * 1280 + 1024 + dk);
        float4 a = s4[0], b = s4[1];
        u16x8 o;
        o[0] = f2bf(a.x); o[1] = f2bf(a.y); o[2] = f2bf(a.z); o[3] = f2bf(a.w);
        o[4] = f2bf(b.x); o[5] = f2bf(b.y); o[6] = f2bf(b.z); o[7] = f2bf(b.w);
        *reinterpret_cast<u16x8*>(w3bbf + idx) = o;
        return;
    }
    if (blk < 160) {
        // ---- table build: exact 20-step RK4 at gamma = gid * TBL_STEP ----
        int gid = (blk - 144) * 256 + threadIdx.x;   // 0..4095

        float c[21];
#pragma unroll
        for (int g = 0; g < 21; ++g) c[g] = 0.f;
        {
            float wv[10];
#pragma unroll
            for (int t = 0; t < 10; ++t) wv[t] = wp[t];
            float m = wv[0];
#pragma unroll
            for (int t = 1; t < 10; ++t) m = fmaxf(m, wv[t]);
            float s = 0.f;
#pragma unroll
            for (int t = 0; t < 10; ++t) { wv[t] = __expf(wv[t] - m); s += wv[t]; }
            float inv = 1.f / s;
            const int   idxs[10]  = {0, 2, 4, 6, 8, 11, 13, 15, 17, 19};
            const float fracs[10] = {0.f, 0.22222222f, 0.44444445f, 0.6666667f, 0.8888889f,
                                     0.11111111f, 0.33333334f, 0.5555556f, 0.7777778f, 1.0f};
#pragma unroll
            for (int t = 0; t < 10; ++t) {
                float w = wv[t] * inv;
                c[idxs[t]]     += w * (1.f - fracs[t]);
                c[idxs[t] + 1] += w * fracs[t];
            }
        }

        float gamma = gid * TBL_STEP;
        float gp = gamma * INVPI;
        float y = 0.f, acc = 0.f;
#pragma unroll
        for (int st = 0; st < 20; ++st) {
            float k1 = feval(y, gp);
            float k2 = feval(fmaf(0.05f, k1, y), gp);
            float k3 = feval(fmaf(0.05f, k2, y), gp);
            float k4 = feval(fmaf(0.1f,  k3, y), gp);
            float sm = k1 + k4;
            sm = fmaf(2.f, k2, sm);
            sm = fmaf(2.f, k3, sm);
            y  = fmaf(0.1f / 6.0f, sm, y);
            acc = fmaf(c[st + 1], y, acc);
        }
        tbl[gid] = acc;
        return;
    }
    // ---- w3a transpose: w3aT[c*128 + j] = w3W[j*1280 + c], c<1024 ----
    {
        int i = (blk - 160) * 256 + threadIdx.x;   // 0..131071
        int c = i & 1023, j = i >> 10;             // coalesced read over c
        w3aT[c * 128 + j] = w3W[j * 1280 + c];
    }
}

// ---------------- K1: feature = relu(x@w1^T+b1) ; yt = lerp(tbl, feature) ----------------
__global__ void __launch_bounds__(256) k_feat(
    const float* __restrict__ x, const float* __restrict__ w1W, const float* __restrict__ w1b,
    const float* __restrict__ tbl,
    unsigned short* __restrict__ featbf, unsigned short* __restrict__ ytbf) {

    __shared__ float tl[TBL_N];
    {
        const float4* g4 = reinterpret_cast<const float4*>(tbl);
        float4* l4 = reinterpret_cast<float4*>(tl);
#pragma unroll
        for (int r = 0; r < 4; ++r) l4[r * 256 + threadIdx.x] = g4[r * 256 + threadIdx.x];
    }
    __syncthreads();

    int tid  = blockIdx.x * 256 + threadIdx.x;    // 819,200 threads
    int base = tid * 8;
    int row  = base >> 8;        // 0..25599
    int d0   = base & 255;       // multiple of 8

    float x0 = x[row * 3 + 0], x1 = x[row * 3 + 1], x2v = x[row * 3 + 2];

    float wreg[24];
    {
        const float4* w4 = reinterpret_cast<const float4*>(w1W + d0 * 3);
#pragma unroll
        for (int q = 0; q < 6; ++q) *reinterpret_cast<float4*>(&wreg[q * 4]) = w4[q];
    }
    float bb[8];
    {
        const float4* b4 = reinterpret_cast<const float4*>(w1b + d0);
        *reinterpret_cast<float4*>(&bb[0]) = b4[0];
        *reinterpret_cast<float4*>(&bb[4]) = b4[1];
    }

    u16x8 fbv, ybv;
#pragma unroll
    for (int j = 0; j < 8; ++j) {
        float g = fmaf(x0, wreg[j * 3], fmaf(x1, wreg[j * 3 + 1], fmaf(x2v, wreg[j * 3 + 2], bb[j])));
        g = fmaxf(g, 0.f);
        fbv[j] = f2bf(g);
        float t = g * TBL_SCALE;
        int i = (int)t;
        i = (i > TBL_N - 2) ? (TBL_N - 2) : i;
        float fr = t - (float)i;
        float a = tl[i], b = tl[i + 1];
        ybv[j] = f2bf(fmaf(fr, b - a, a));
    }
    *reinterpret_cast<u16x8*>(featbf + base) = fbv;
    *reinterpret_cast<u16x8*>(ytbf + base) = ybv;
}

// ---------------- K2: GEMM2 + relu + max over n + v-partial ----------------
// 1024 blocks = 256 batches x 4 col-quarters, XCD-chunked.
// Stage A via global_load_lds (linear LDS dest, inverse-swizzled global src);
// MFMA main loop; in-block max epilogue; then v-partial:
//   vpart[b][q][j] = sum_{c in quarter} x2max[c] * w3a[j][c]   (f32, w3aT layout)
__global__ void __launch_bounds__(256, 2) k_gemm2max(
    const unsigned short* __restrict__ featbf, const unsigned short* __restrict__ w2bf,
    const float* __restrict__ w2bias, const float* __restrict__ w3aT,
    float* __restrict__ vpart) {

    __shared__ __align__(1024) char smem[57344];   // As: 112 rows x 512 B

    int p = blockIdx.x;
    int xcd = p & 7, slot = p >> 3;
    int b = xcd * 32 + (slot >> 2);    // batches chunked 32-per-XCD
    int q = slot & 3;                  // col quarter (256 cols)

    int wave = threadIdx.x >> 6, lane = threadIdx.x & 63;
    int col16 = lane & 15, krow = lane >> 4;
    int colbase = q * 256 + wave * 64;

    // ---- B prefetch (first k0) issues before staging ----
    const unsigned short* bp = w2bf + (size_t)(colbase + col16) * 256 + krow * 8;
    bf16x8 Bcur[4], Bnxt[4];
#pragma unroll
    for (int ct = 0; ct < 4; ++ct)
        Bcur[ct] = *reinterpret_cast<const bf16x8*>(bp + ct * 4096);

    // ---- stage A: pairs of rows (1 KB each); wave w owns pairs {w, w+4, ...} ----
    // LDS linear; read-side swizzle is byte ch'=ch^(row&7), an involution, applied
    // to the GLOBAL source address here (rule: gload_lds writes base+lane*16).
    {
        const unsigned short* src = featbf + (size_t)b * 25600;
        int r_in_pair = lane >> 5;           // 0..1
        int chp = lane & 31;                 // linear 16B chunk in row
#pragma unroll
        for (int k = 0; k < 14; ++k) {
            int pr = wave + k * 4;           // pair index 0..55
            int row = pr * 2 + r_in_pair;
            if (pr < 50) {
                int ch = chp ^ (row & 7);
                const unsigned short* g = src + row * 256 + ch * 8;
                __builtin_amdgcn_global_load_lds(
                    (const __attribute__((address_space(1))) void*)g,
                    (__attribute__((address_space(3))) void*)(smem + pr * 1024),
                    16, 0, 0);
            } else {
                // rows 100..111: zero padding (read side still applies XOR; zeros ok)
                *reinterpret_cast<f32x4*>(smem + pr * 1024 + lane * 16) = (f32x4){0.f,0.f,0.f,0.f};
            }
        }
    }
    __syncthreads();

    int sw = (col16 & 7) << 4;

    f32x4 acc[7][4];
#pragma unroll
    for (int mt = 0; mt < 7; ++mt)
#pragma unroll
        for (int ct = 0; ct < 4; ++ct) acc[mt][ct] = (f32x4){0.f, 0.f, 0.f, 0.f};

    const char* Ab = (const char*)smem;
#pragma unroll
    for (int k0 = 0; k0 < 8; ++k0) {
        int off = (k0 * 64 + krow * 16) ^ sw;
        bf16x8 Af[7];
#pragma unroll
        for (int mt = 0; mt < 7; ++mt)
            Af[mt] = *reinterpret_cast<const bf16x8*>(Ab + (mt * 16 + col16) * 512 + off);
        if (k0 < 7) {
#pragma unroll
            for (int ct = 0; ct < 4; ++ct)
                Bnxt[ct] = *reinterpret_cast<const bf16x8*>(bp + ct * 4096 + (k0 + 1) * 32);
        }
#pragma unroll
        for (int mt = 0; mt < 7; ++mt)
#pragma unroll
            for (int ct = 0; ct < 4; ++ct)
                acc[mt][ct] = MFMA16(Af[mt], Bcur[ct], acc[mt][ct]);
#pragma unroll
        for (int ct = 0; ct < 4; ++ct) Bcur[ct] = Bnxt[ct];
    }

    // ---- epilogue: relu(acc+bias), max over valid rows n<100 ----
    float bias[4], m[4];
#pragma unroll
    for (int ct = 0; ct < 4; ++ct) {
        bias[ct] = w2bias[colbase + ct * 16 + col16];
        m[ct] = 0.f;   // true max >= 0 (relu over 100 valid rows)
    }
#pragma unroll
    for (int mt = 0; mt < 7; ++mt) {
#pragma unroll
        for (int r = 0; r < 4; ++r) {
            int n = mt * 16 + krow * 4 + r;
            bool valid = n < 100;
#pragma unroll
            for (int ct = 0; ct < 4; ++ct) {
                float v = fmaxf(acc[mt][ct][r] + bias[ct], 0.f);
                if (valid) m[ct] = fmaxf(m[ct], v);
            }
        }
    }
#pragma unroll
    for (int ct = 0; ct < 4; ++ct) {
        m[ct] = fmaxf(m[ct], __shfl_xor(m[ct], 16));
        m[ct] = fmaxf(m[ct], __shfl_xor(m[ct], 32));
    }

    // ---- v-partial: vpart[b][q][j] = sum_c xs[c] * w3aT[q*256+c][j] ----
    float* xs = (float*)smem;           // 256 f32 (quarter's x2max), aliases As
    float* p0s = xs + 256;              // 128 f32 partial (c-half 0)
    float* p1s = xs + 384;              // 128 f32 partial (c-half 1)

    __syncthreads();                    // everyone done reading As
    if (lane < 16) {
#pragma unroll
        for (int ct = 0; ct < 4; ++ct)
            xs[wave * 64 + ct * 16 + lane] = m[ct];
    }
    __syncthreads();

    {
        int j = (wave & 1) * 64 + lane;            // output index 0..127
        int ch = wave >> 1;                        // c-half
        const float* wt = w3aT + (size_t)(q * 256 + ch * 128) * 128 + j;
        float s0 = 0.f, s1 = 0.f;
#pragma unroll 8
        for (int c = 0; c < 128; c += 2) {
            s0 = fmaf(xs[ch * 128 + c],     wt[(size_t)c * 128],       s0);
            s1 = fmaf(xs[ch * 128 + c + 1], wt[(size_t)(c + 1) * 128], s1);
        }
        float* dst = (ch == 0) ? p0s : p1s;
        dst[j] = s0 + s1;
    }
    __syncthreads();
    if (threadIdx.x < 128)
        vpart[(size_t)b * 512 + q * 128 + threadIdx.x] = p0s[threadIdx.x] + p1s[threadIdx.x];
}

// ---------------- K3: h3 = relu(v_b + yt @ w3b^T) ; out = h3 @ outW^T + outb ----------------
// grid 800: 32 rows per block; 4 waves, wave owns 32 cols (2 n-tiles)
__global__ void __launch_bounds__(256) k_final(
    const unsigned short* __restrict__ ytbf, const unsigned short* __restrict__ w3bbf,
    const float* __restrict__ vpart, const float* __restrict__ w3bias,
    const float* __restrict__ outW, const float* __restrict__ outb,
    float* __restrict__ out) {

    __shared__ float h3s[32][132];
    int rbase = blockIdx.x * 32;
    int wave = threadIdx.x >> 6, lane = threadIdx.x & 63;
    int col16 = lane & 15, krow = lane >> 4;

    const unsigned short* ap0 = ytbf + (size_t)(rbase + col16) * 256 + krow * 8;
    const unsigned short* ap1 = ap0 + 16 * 256;
    const unsigned short* bp0 = w3bbf + (size_t)(wave * 32 + col16) * 256 + krow * 8;
    const unsigned short* bp1 = bp0 + 16 * 256;

    f32x4 a00 = {0.f,0.f,0.f,0.f}, a01 = {0.f,0.f,0.f,0.f};
    f32x4 a10 = {0.f,0.f,0.f,0.f}, a11 = {0.f,0.f,0.f,0.f};
#pragma unroll
    for (int k0 = 0; k0 < 8; ++k0) {
        bf16x8 A0 = *reinterpret_cast<const bf16x8*>(ap0 + k0 * 32);
        bf16x8 A1 = *reinterpret_cast<const bf16x8*>(ap1 + k0 * 32);
        bf16x8 B0 = *reinterpret_cast<const bf16x8*>(bp0 + k0 * 32);
        bf16x8 B1 = *reinterpret_cast<const bf16x8*>(bp1 + k0 * 32);
        a00 = MFMA16(A0, B0, a00);
        a01 = MFMA16(A0, B1, a01);
        a10 = MFMA16(A1, B0, a10);
        a11 = MFMA16(A1, B1, a11);
    }

#pragma unroll
    for (int mt = 0; mt < 2; ++mt) {
#pragma unroll
        for (int nt = 0; nt < 2; ++nt) {
            f32x4 acc = (mt == 0) ? ((nt == 0) ? a00 : a01) : ((nt == 0) ? a10 : a11);
#pragma unroll
            for (int r = 0; r < 4; ++r) {
                int rloc  = mt * 16 + krow * 4 + r;
                int rglob = rbase + rloc;
                int bb    = rglob / 100;
                int col   = wave * 32 + nt * 16 + col16;
                const float* vp = vpart + (size_t)bb * 512;
                float vsum = (vp[col] + vp[128 + col]) + (vp[256 + col] + vp[384 + col]);
                float h = acc[r] + vsum + w3bias[col];
                h3s[rloc][col] = fmaxf(h, 0.f);
            }
        }
    }
    __syncthreads();

    int r  = threadIdx.x >> 3;   // 0..31
    int jg = threadIdx.x & 7;    // 0..7
    float p0 = 0.f, p1 = 0.f;
#pragma unroll
    for (int t = 0; t < 16; ++t) {
        int j = jg * 16 + t;
        float h = h3s[r][j];
        p0 = fmaf(h, outW[j], p0);
        p1 = fmaf(h, outW[128 + j], p1);
    }
    p0 += __shfl_xor(p0, 1); p0 += __shfl_xor(p0, 2); p0 += __shfl_xor(p0, 4);
    p1 += __shfl_xor(p1, 1); p1 += __shfl_xor(p1, 2); p1 += __shfl_xor(p1, 4);
    if (jg == 0) {
        int rg = rbase + r;
        out[rg * 2 + 0] = p0 + outb[0];
        out[rg * 2 + 1] = p1 + outb[1];
    }
}

extern "C" void kernel_launch(void* const* d_in, const int* in_sizes, int n_in,
                              void* d_out, int out_size, void* d_ws, size_t ws_size,
                              hipStream_t stream) {
    const float* x    = (const float*)d_in[0];
    const float* w1W  = (const float*)d_in[1];
    const float* w1b  = (const float*)d_in[2];
    const float* w2W  = (const float*)d_in[3];
    const float* w2b  = (const float*)d_in[4];
    const float* w3W  = (const float*)d_in[5];
    const float* w3b  = (const float*)d_in[6];
    const float* outW = (const float*)d_in[7];
    const float* outb = (const float*)d_in[8];
    const float* wp   = (const float*)d_in[9];
    float* out = (float*)d_out;

    char* ws = (char*)d_ws;
    unsigned short* featbf = (unsigned short*)(ws);                 // 13,107,200 B
    unsigned short* ytbf   = (unsigned short*)(ws + 13107200);      // 13,107,200 B
    unsigned short* w2bf_  = (unsigned short*)(ws + 26214400);      // 524,288 B
    unsigned short* w3bbf_ = (unsigned short*)(ws + 26738688);      // 65,536 B
    float* tbl             = (float*)(ws + 26804224);               // 16,384 B
    float* vpart           = (float*)(ws + 26820608);               // 256*4*128 f32 = 524,288 B
    float* w3aT            = (float*)(ws + 27344896);               // 1024*128 f32 = 524,288 B
    // total ws use: 27,869,184 B

    k_prep<<<672, 256, 0, stream>>>(w2W, w3W, wp, w2bf_, w3bbf_, tbl, w3aT);
    k_feat<<<3200, 256, 0, stream>>>(x, w1W, w1b, tbl, featbf, ytbf);
    k_gemm2max<<<1024, 256, 0, stream>>>(featbf, w2bf_, w2b, w3aT, vpart);
    k_final<<<800, 256, 0, stream>>>(ytbf, w3bbf_, vpart, w3b, outW, outb, out);
}